// Round 1
// baseline (225.379 us; speedup 1.0000x reference)
//
#include <hip/hip_runtime.h>
#include <hip/hip_bf16.h>
#include <math.h>

#define N_TOK 8192
#define DIM   512
#define HID   1024
#define NEXP  8

typedef __attribute__((ext_vector_type(8))) __bf16 bf16x8;
typedef __attribute__((ext_vector_type(4))) float  f32x4;

static __device__ __forceinline__ unsigned short f2bf(float f) {
    unsigned int u = __builtin_bit_cast(unsigned int, f);
    unsigned int r = u + 0x7fffu + ((u >> 16) & 1u);   // RNE
    return (unsigned short)(r >> 16);
}

// ---------------- prep: x->bf16, W1/W2 -> packed bf16 B-fragment layout ----
// W1p block layout: ((e*64 + nb)*16 + kb)*512 + lane*8 + j
//   holds W1[e][d = kb*32 + (lane>>4)*8 + j][h = nb*16 + (lane&15)]
// W2p block layout: ((e*32 + nb)*32 + kb)*512 + lane*8 + j
//   holds W2[e][h = kb*32 + (lane>>4)*8 + j][d = nb*16 + (lane&15)]
__global__ __launch_bounds__(256) void prep_kernel(
    const float* __restrict__ x, const float* __restrict__ W1,
    const float* __restrict__ W2, unsigned short* __restrict__ xb,
    unsigned short* __restrict__ W1p, unsigned short* __restrict__ W2p,
    int* __restrict__ counts)
{
    int bid = blockIdx.x;
    int tin = threadIdx.x;
    if (bid == 0 && tin < NEXP) counts[tin] = 0;
    if (bid < 2048) {
        int t = bid * 256 + tin;                       // 524288 threads, 8 elems each
        const float4* xin = (const float4*)x + (size_t)t * 2;
        float4 a = xin[0], b = xin[1];
        unsigned short u[8];
        u[0]=f2bf(a.x); u[1]=f2bf(a.y); u[2]=f2bf(a.z); u[3]=f2bf(a.w);
        u[4]=f2bf(b.x); u[5]=f2bf(b.y); u[6]=f2bf(b.z); u[7]=f2bf(b.w);
        *reinterpret_cast<uint4*>(xb + (size_t)t * 8) = *reinterpret_cast<const uint4*>(u);
    } else if (bid < 4096) {
        int tid = (bid - 2048) * 256 + tin;
        int l = tid & 63, kb = (tid >> 6) & 15, nb = (tid >> 10) & 63, e = tid >> 16;
        int d0 = kb * 32 + (l >> 4) * 8;
        int h  = nb * 16 + (l & 15);
        const float* src = W1 + (size_t)e * DIM * HID + (size_t)d0 * HID + h;
        unsigned short u[8];
        #pragma unroll
        for (int j = 0; j < 8; j++) u[j] = f2bf(src[(size_t)j * HID]);
        size_t o = (((size_t)(e * 64 + nb) * 16 + kb) * 64 + l) * 8;
        *reinterpret_cast<uint4*>(W1p + o) = *reinterpret_cast<const uint4*>(u);
    } else {
        int tid = (bid - 4096) * 256 + tin;
        int l = tid & 63, kb = (tid >> 6) & 31, nb = (tid >> 11) & 31, e = tid >> 16;
        int h0 = kb * 32 + (l >> 4) * 8;
        int d  = nb * 16 + (l & 15);
        const float* src = W2 + (size_t)e * HID * DIM + (size_t)h0 * DIM + d;
        unsigned short u[8];
        #pragma unroll
        for (int j = 0; j < 8; j++) u[j] = f2bf(src[(size_t)j * DIM]);
        size_t o = (((size_t)(e * 32 + nb) * 32 + kb) * 64 + l) * 8;
        *reinterpret_cast<uint4*>(W2p + o) = *reinterpret_cast<const uint4*>(u);
    }
}

// ---------------- router: logits, softmax, top-2, scatter to expert lists --
__global__ __launch_bounds__(256) void router_kernel(
    const float* __restrict__ x, const float* __restrict__ Wr,
    const float* __restrict__ br, int* __restrict__ counts,
    int* __restrict__ tlist, float* __restrict__ glist)
{
    int slot = threadIdx.x >> 3, e = threadIdx.x & 7;
    int t = blockIdx.x * 32 + slot;
    const float4* xr = (const float4*)(x + (size_t)t * DIM);
    const float4* wr = (const float4*)(Wr + (size_t)e * DIM);
    float acc = 0.f;
    #pragma unroll 4
    for (int i = 0; i < DIM / 4; i++) {
        float4 a = xr[i], b = wr[i];
        acc += a.x * b.x + a.y * b.y + a.z * b.z + a.w * b.w;
    }
    acc += br[e];
    __shared__ float lg[32][8];
    lg[slot][e] = acc;
    __syncthreads();
    if (e == 0) {
        float l0[8];
        #pragma unroll
        for (int i = 0; i < 8; i++) l0[i] = lg[slot][i];
        int i1 = 0; float m1 = l0[0];
        #pragma unroll
        for (int i = 1; i < 8; i++) if (l0[i] > m1) { m1 = l0[i]; i1 = i; }
        float sum = 0.f;
        #pragma unroll
        for (int i = 0; i < 8; i++) sum += expf(l0[i] - m1);
        int i2 = 0; float m2 = -1e30f;
        #pragma unroll
        for (int i = 0; i < 8; i++) if (i != i1 && l0[i] > m2) { m2 = l0[i]; i2 = i; }
        float inv = 1.f / sum;
        float p1 = inv;                    // expf(0)*inv
        float p2 = expf(m2 - m1) * inv;
        int pos1 = atomicAdd(&counts[i1], 1);
        tlist[i1 * N_TOK + pos1] = t * 2;     glist[i1 * N_TOK + pos1] = p1;
        int pos2 = atomicAdd(&counts[i2], 1);
        tlist[i2 * N_TOK + pos2] = t * 2 + 1; glist[i2 * N_TOK + pos2] = p2;
    }
}

// ---------------- fused per-expert FFN: fc1 + GELU + fc2 -------------------
__global__ __launch_bounds__(512, 1) void ffn_kernel(
    const unsigned short* __restrict__ xb,
    const unsigned short* __restrict__ W1p,
    const unsigned short* __restrict__ W2p,
    const float* __restrict__ b1, const float* __restrict__ b2,
    const int* __restrict__ counts, const int* __restrict__ tlist,
    const float* __restrict__ glist, float* __restrict__ opair)
{
    const int e = blockIdx.y;
    const int cnt = counts[e];
    const int m0 = blockIdx.x * 64;
    if (m0 >= cnt) return;
    const int nvalid = min(64, cnt - m0);

    __shared__ __align__(16) unsigned short xs[64 * 512]; // swizzled bf16 x tile
    __shared__ __align__(16) unsigned short hs[64 * 128]; // swizzled bf16 h chunk
    __shared__ int   tls[64];
    __shared__ float gls[64];

    const int tid = threadIdx.x;
    const int w = tid >> 6, lane = tid & 63;
    const int lg_ = lane >> 4, lm = lane & 15;

    if (tid < 64) {
        int idx = m0 + tid;
        int src = (idx < cnt) ? idx : m0;
        tls[tid] = tlist[e * N_TOK + src];
        gls[tid] = (idx < cnt) ? glist[e * N_TOK + src] : 0.f;
    }
    __syncthreads();

    // stage gathered x rows into swizzled LDS (wave w: rows [8w, 8w+8))
    #pragma unroll
    for (int i = 0; i < 8; i++) {
        int row = w * 8 + i;
        int token = tls[row] >> 1;
        uint4 v = *(reinterpret_cast<const uint4*>(xb + (size_t)token * DIM) + lane);
        int bo = row * 1024 + ((lane * 16) ^ ((row & 7) << 4));
        *reinterpret_cast<uint4*>(reinterpret_cast<char*>(xs) + bo) = v;
    }
    __syncthreads();

    f32x4 acc2[4][4];
    #pragma unroll
    for (int a = 0; a < 4; a++)
        #pragma unroll
        for (int b = 0; b < 4; b++) acc2[a][b] = (f32x4)0.f;

    for (int chunk = 0; chunk < 8; chunk++) {
        // fc1: wave's 16-col slice of h-chunk, K = 512
        f32x4 acc1[4];
        #pragma unroll
        for (int a = 0; a < 4; a++) acc1[a] = (f32x4)0.f;
        const int nb = chunk * 8 + w;
        const uint4* w1base = reinterpret_cast<const uint4*>(W1p)
                              + ((size_t)(e * 64 + nb) * 16) * 64 + lane;
        #pragma unroll
        for (int kb = 0; kb < 16; kb++) {
            bf16x8 bf = __builtin_bit_cast(bf16x8, w1base[kb * 64]);
            #pragma unroll
            for (int rt = 0; rt < 4; rt++) {
                int row = rt * 16 + lm;
                int bo = row * 1024 + ((kb * 64 + lg_ * 16) ^ ((row & 7) << 4));
                bf16x8 af = __builtin_bit_cast(bf16x8,
                    *reinterpret_cast<const uint4*>(reinterpret_cast<const char*>(xs) + bo));
                acc1[rt] = __builtin_amdgcn_mfma_f32_16x16x32_bf16(af, bf, acc1[rt], 0, 0, 0);
            }
        }
        float b1v = b1[e * HID + chunk * 128 + w * 16 + lm];
        __syncthreads();            // prior fc2 reads of hs are done
        #pragma unroll
        for (int rt = 0; rt < 4; rt++) {
            #pragma unroll
            for (int r = 0; r < 4; r++) {
                float v = acc1[rt][r] + b1v;
                float g = 0.5f * v * (1.f + erff(v * 0.7071067811865475f));
                int hrow = rt * 16 + lg_ * 4 + r;
                int hcol = w * 16 + lm;
                int bo = hrow * 256 + ((hcol * 2) ^ ((hrow & 7) << 4));
                *reinterpret_cast<unsigned short*>(reinterpret_cast<char*>(hs) + bo) = f2bf(g);
            }
        }
        __syncthreads();
        // fc2: wave's 64-col slab, K-chunk = 128
        const uint4* w2base = reinterpret_cast<const uint4*>(W2p)
                              + ((size_t)(e * 32 + w * 4) * 32 + chunk * 4) * 64 + lane;
        #pragma unroll
        for (int ks = 0; ks < 4; ks++) {
            bf16x8 af[4];
            #pragma unroll
            for (int rt = 0; rt < 4; rt++) {
                int row = rt * 16 + lm;
                int bo = row * 256 + ((ks * 64 + lg_ * 16) ^ ((row & 7) << 4));
                af[rt] = __builtin_bit_cast(bf16x8,
                    *reinterpret_cast<const uint4*>(reinterpret_cast<const char*>(hs) + bo));
            }
            #pragma unroll
            for (int j = 0; j < 4; j++) {
                bf16x8 bf = __builtin_bit_cast(bf16x8, w2base[j * 2048 + ks * 64]);
                #pragma unroll
                for (int rt = 0; rt < 4; rt++)
                    acc2[rt][j] = __builtin_amdgcn_mfma_f32_16x16x32_bf16(af[rt], bf, acc2[rt][j], 0, 0, 0);
            }
        }
    }

    // epilogue: gate * (o + b2) -> opair[t*2+k][:]
    #pragma unroll
    for (int j = 0; j < 4; j++) {
        int ocol = w * 64 + j * 16 + lm;
        float b2v = b2[e * DIM + ocol];
        #pragma unroll
        for (int rt = 0; rt < 4; rt++) {
            #pragma unroll
            for (int r = 0; r < 4; r++) {
                int orow = rt * 16 + lg_ * 4 + r;
                if (orow < nvalid) {
                    int entry = tls[orow];
                    float gate = gls[orow];
                    opair[(size_t)entry * DIM + ocol] = gate * (acc2[rt][j][r] + b2v);
                }
            }
        }
    }
}

// ---------------- combine: y[t] = opair[t][0] + opair[t][1] ----------------
__global__ __launch_bounds__(256) void combine_kernel(
    const float* __restrict__ opair, float* __restrict__ y)
{
    int n = blockIdx.x * 256 + threadIdx.x;   // over N*D/4
    int t = n >> 7, d4 = n & 127;
    const float4* o4 = (const float4*)opair;
    float4 a = o4[(size_t)(t * 2) * 128 + d4];
    float4 b = o4[(size_t)(t * 2 + 1) * 128 + d4];
    float4 r; r.x = a.x + b.x; r.y = a.y + b.y; r.z = a.z + b.z; r.w = a.w + b.w;
    reinterpret_cast<float4*>(y)[n] = r;
}

extern "C" void kernel_launch(void* const* d_in, const int* in_sizes, int n_in,
                              void* d_out, int out_size, void* d_ws, size_t ws_size,
                              hipStream_t stream)
{
    const float* x  = (const float*)d_in[0];
    const float* Wr = (const float*)d_in[1];
    const float* br = (const float*)d_in[2];
    const float* W1 = (const float*)d_in[3];
    const float* b1 = (const float*)d_in[4];
    const float* W2 = (const float*)d_in[5];
    const float* b2 = (const float*)d_in[6];
    float* y = (float*)d_out;

    char* ws = (char*)d_ws;
    int*   counts = (int*)ws;                                   // 32 B (padded 256)
    int*   tlist  = (int*)(ws + 256);                           // E*N*4 = 256 KB
    float* glist  = (float*)(ws + 256 + 262144);                // 256 KB
    unsigned short* xb  = (unsigned short*)(ws + 256 + 524288); // 8 MB
    unsigned short* W1p = xb  + (size_t)N_TOK * DIM;            // 8 MB
    unsigned short* W2p = W1p + (size_t)NEXP * DIM * HID;       // 8 MB
    float* opair = (float*)(W2p + (size_t)NEXP * HID * DIM);    // 32 MB

    prep_kernel<<<6144, 256, 0, stream>>>(x, W1, W2, xb, W1p, W2p, counts);
    router_kernel<<<256, 256, 0, stream>>>(x, Wr, br, counts, tlist, glist);
    ffn_kernel<<<dim3(128, 8), 512, 0, stream>>>(xb, W1p, W2p, b1, b2,
                                                 counts, tlist, glist, opair);
    combine_kernel<<<4096, 256, 0, stream>>>(opair, y);
}

// Round 2
// 203.088 us; speedup vs baseline: 1.1098x; 1.1098x over previous
//
#include <hip/hip_runtime.h>
#include <hip/hip_bf16.h>
#include <math.h>

#define N_TOK 8192
#define DIM   512
#define HID   1024
#define NEXP  8

typedef __attribute__((ext_vector_type(8))) __bf16 bf16x8;
typedef __attribute__((ext_vector_type(4))) float  f32x4;

static __device__ __forceinline__ unsigned short f2bf(float f) {
    unsigned int u = __builtin_bit_cast(unsigned int, f);
    unsigned int r = u + 0x7fffu + ((u >> 16) & 1u);   // RNE
    return (unsigned short)(r >> 16);
}

// ---------------- prep: x->bf16, W1/W2 -> packed bf16 fragment layout ------
// W1p frag (e, nb<64, kb<16): lane l, elem j = W1[e][d=kb*32+(l>>4)*8+j][h=nb*16+(l&15)]
// W2p frag (e, nb<32, kb<32): lane l, elem j = W2[e][h=kb*32+(l>>4)*8+j][d=nb*16+(l&15)]
// (identical layout to the round-1 passing kernel; produced via LDS transpose
//  so both the global read and the global write are >=512B coalesced)
__global__ __launch_bounds__(256) void prep_kernel(
    const float* __restrict__ x, const float* __restrict__ W1,
    const float* __restrict__ W2, unsigned short* __restrict__ xb,
    unsigned short* __restrict__ W1p, unsigned short* __restrict__ W2p,
    int* __restrict__ counts)
{
    __shared__ unsigned short lt[32][128];
    int bid = blockIdx.x;
    int tin = threadIdx.x;
    if (bid == 0 && tin < NEXP) counts[tin] = 0;
    if (bid < 2048) {
        int t = bid * 256 + tin;                       // x -> bf16, 8 elems/thread
        const float4* xin = (const float4*)x + (size_t)t * 2;
        float4 a = xin[0], b = xin[1];
        unsigned short u[8];
        u[0]=f2bf(a.x); u[1]=f2bf(a.y); u[2]=f2bf(a.z); u[3]=f2bf(a.w);
        u[4]=f2bf(b.x); u[5]=f2bf(b.y); u[6]=f2bf(b.z); u[7]=f2bf(b.w);
        *reinterpret_cast<uint4*>(xb + (size_t)t * 8) = *reinterpret_cast<const uint4*>(u);
        return;
    }
    // W transpose path: block covers 32 in-rows x 128 out-cols
    int e, kb, seg, OUTD;
    const float* W;
    if (bid < 3072) {           // W1: 8e x 16kb x 8seg
        int b = bid - 2048;
        e = b >> 7; kb = (b >> 3) & 15; seg = b & 7;
        OUTD = HID;
        W = W1 + (size_t)e * DIM * HID + (size_t)(kb * 32) * HID + seg * 128;
    } else {                    // W2: 8e x 32kb x 4seg
        int b = bid - 3072;
        e = b >> 7; kb = (b >> 2) & 31; seg = b & 3;
        OUTD = DIM;
        W = W2 + (size_t)e * HID * DIM + (size_t)(kb * 32) * DIM + seg * 128;
    }
    #pragma unroll
    for (int i = 0; i < 4; i++) {                      // coalesced 512B-segment reads
        int fl = i * 256 + tin;
        int r = fl >> 5, c4 = fl & 31;
        float4 v = *reinterpret_cast<const float4*>(W + (size_t)r * OUTD + c4 * 4);
        lt[r][c4*4+0] = f2bf(v.x); lt[r][c4*4+1] = f2bf(v.y);
        lt[r][c4*4+2] = f2bf(v.z); lt[r][c4*4+3] = f2bf(v.w);
    }
    __syncthreads();
    unsigned short* dstp = (bid < 3072) ? W1p : W2p;
    #pragma unroll
    for (int i = 0; i < 2; i++) {                      // packed coalesced writes
        int s = i * 256 + tin;
        int nbl = s >> 6, l = s & 63;
        unsigned short u[8];
        #pragma unroll
        for (int j = 0; j < 8; j++) u[j] = lt[(l >> 4) * 8 + j][nbl * 16 + (l & 15)];
        size_t o;
        if (bid < 3072) o = (((size_t)(e * 64 + seg * 8 + nbl) * 16 + kb) * 64 + l) * 8;
        else            o = (((size_t)(e * 32 + seg * 8 + nbl) * 32 + kb) * 64 + l) * 8;
        *reinterpret_cast<uint4*>(dstp + o) = *reinterpret_cast<const uint4*>(u);
    }
}

// ---------------- router: logits, softmax, top-2, scatter to expert lists --
__global__ __launch_bounds__(256) void router_kernel(
    const float* __restrict__ x, const float* __restrict__ Wr,
    const float* __restrict__ br, int* __restrict__ counts,
    int* __restrict__ tlist, float* __restrict__ glist)
{
    int slot = threadIdx.x >> 3, e = threadIdx.x & 7;
    int t = blockIdx.x * 32 + slot;
    const float4* xr = (const float4*)(x + (size_t)t * DIM);
    const float4* wr = (const float4*)(Wr + (size_t)e * DIM);
    float acc = 0.f;
    #pragma unroll 4
    for (int i = 0; i < DIM / 4; i++) {
        float4 a = xr[i], b = wr[i];
        acc += a.x * b.x + a.y * b.y + a.z * b.z + a.w * b.w;
    }
    acc += br[e];
    __shared__ float lg[32][8];
    lg[slot][e] = acc;
    __syncthreads();
    if (e == 0) {
        float l0[8];
        #pragma unroll
        for (int i = 0; i < 8; i++) l0[i] = lg[slot][i];
        int i1 = 0; float m1 = l0[0];
        #pragma unroll
        for (int i = 1; i < 8; i++) if (l0[i] > m1) { m1 = l0[i]; i1 = i; }
        float sum = 0.f;
        #pragma unroll
        for (int i = 0; i < 8; i++) sum += expf(l0[i] - m1);
        int i2 = 0; float m2 = -1e30f;
        #pragma unroll
        for (int i = 0; i < 8; i++) if (i != i1 && l0[i] > m2) { m2 = l0[i]; i2 = i; }
        float inv = 1.f / sum;
        float p1 = inv;
        float p2 = expf(m2 - m1) * inv;
        int pos1 = atomicAdd(&counts[i1], 1);
        tlist[i1 * N_TOK + pos1] = t * 2;     glist[i1 * N_TOK + pos1] = p1;
        int pos2 = atomicAdd(&counts[i2], 1);
        tlist[i2 * N_TOK + pos2] = t * 2 + 1; glist[i2 * N_TOK + pos2] = p2;
    }
}

// ---------------- fused per-expert FFN (transposed tiles: hT, oT) ----------
// fc1: hT[h][t] = mfma(A=W1frag, B=xfrag)  -> lane holds h = tile*16+lg*4+r, t = lm
// fc2: oT[d][t] = mfma(A=W2frag, B=hfrag)  -> lane holds d = tile*16+lg*4+r, t = lm
__global__ __launch_bounds__(512, 1) void ffn_kernel(
    const unsigned short* __restrict__ xb,
    const unsigned short* __restrict__ W1p,
    const unsigned short* __restrict__ W2p,
    const float* __restrict__ b1, const float* __restrict__ b2,
    const int* __restrict__ counts, const int* __restrict__ tlist,
    const float* __restrict__ glist, float* __restrict__ opair)
{
    const int e = blockIdx.y;
    const int cnt = counts[e];
    const int m0 = blockIdx.x * 64;
    if (m0 >= cnt) return;
    const int nvalid = min(64, cnt - m0);

    __shared__ __align__(16) unsigned short xs[64 * 512]; // swizzled x tile  (64 KB)
    __shared__ __align__(16) unsigned short hs[64 * 512]; // swizzled hT chunk (64 KB)
    __shared__ int   tls[64];
    __shared__ float gls[64];

    const int tid = threadIdx.x;
    const int w = tid >> 6, lane = tid & 63;
    const int lg_ = lane >> 4, lm = lane & 15;

    if (tid < 64) {
        int idx = m0 + tid;
        int src = (idx < cnt) ? idx : m0;
        tls[tid] = tlist[e * N_TOK + src];
        gls[tid] = (idx < cnt) ? glist[e * N_TOK + src] : 0.f;
    }
    __syncthreads();

    // stage gathered x rows into swizzled LDS (wave w: rows [8w, 8w+8))
    #pragma unroll
    for (int i = 0; i < 8; i++) {
        int row = w * 8 + i;
        int token = tls[row] >> 1;
        uint4 v = *(reinterpret_cast<const uint4*>(xb + (size_t)token * DIM) + lane);
        int bo = row * 1024 + ((lane * 16) ^ ((row & 7) << 4));
        *reinterpret_cast<uint4*>(reinterpret_cast<char*>(xs) + bo) = v;
    }
    __syncthreads();

    const char* xsb = reinterpret_cast<const char*>(xs);
    char* hsb = reinterpret_cast<char*>(hs);

    f32x4 acc2[4][4];                    // [d-tile][t-tile], persistent over K
    #pragma unroll
    for (int a = 0; a < 4; a++)
        #pragma unroll
        for (int b = 0; b < 4; b++) acc2[a][b] = (f32x4)0.f;

    for (int c = 0; c < 2; c++) {        // H chunk of 512
        // ---- fc1: wave owns 4 h-tiles (h = (c*32 + w*4 + i)*16) x 4 t-tiles
        f32x4 acc1[4][4];                // [h-tile][t-tile]
        #pragma unroll
        for (int a = 0; a < 4; a++)
            #pragma unroll
            for (int b = 0; b < 4; b++) acc1[a][b] = (f32x4)0.f;
        const uint4* w1base = reinterpret_cast<const uint4*>(W1p)
            + ((size_t)(e * 64 + c * 32 + w * 4) * 16) * 64 + lane;
        #pragma unroll
        for (int kb = 0; kb < 16; kb++) {
            bf16x8 aw[4];
            #pragma unroll
            for (int i = 0; i < 4; i++)
                aw[i] = __builtin_bit_cast(bf16x8, w1base[(size_t)(i * 16 + kb) * 64]);
            #pragma unroll
            for (int tt = 0; tt < 4; tt++) {
                int row = tt * 16 + lm;
                int bo = row * 1024 + ((kb * 64 + lg_ * 16) ^ ((row & 7) << 4));
                bf16x8 bx = __builtin_bit_cast(bf16x8,
                    *reinterpret_cast<const uint4*>(xsb + bo));
                #pragma unroll
                for (int i = 0; i < 4; i++)
                    acc1[i][tt] = __builtin_amdgcn_mfma_f32_16x16x32_bf16(aw[i], bx, acc1[i][tt], 0, 0, 0);
            }
        }
        __syncthreads();                 // previous fc2 finished reading hs
        // ---- bias + GELU in regs, pack 4 bf16 -> one ds_write_b64 per tile
        #pragma unroll
        for (int i = 0; i < 4; i++) {
            int hloc0 = (w * 4 + i) * 16 + lg_ * 4;     // within-chunk h of r=0
            f32x4 b1v = *reinterpret_cast<const f32x4*>(b1 + (size_t)e * HID + c * 512 + hloc0);
            #pragma unroll
            for (int tt = 0; tt < 4; tt++) {
                int trow = tt * 16 + lm;
                float g[4];
                #pragma unroll
                for (int r = 0; r < 4; r++) {
                    float v = acc1[i][tt][r] + b1v[r];
                    g[r] = 0.5f * v * (1.f + erff(v * 0.7071067811865475f));
                }
                unsigned int p0 = (unsigned int)f2bf(g[0]) | ((unsigned int)f2bf(g[1]) << 16);
                unsigned int p1 = (unsigned int)f2bf(g[2]) | ((unsigned int)f2bf(g[3]) << 16);
                unsigned long long pk = (unsigned long long)p0 | ((unsigned long long)p1 << 32);
                int bo = trow * 1024 + ((hloc0 * 2) ^ ((trow & 7) << 4));
                *reinterpret_cast<unsigned long long*>(hsb + bo) = pk;
            }
        }
        __syncthreads();                 // hs chunk ready
        // ---- fc2: wave owns 4 d-tiles (d = (w*4 + j)*16) x 4 t-tiles, K = 512
        const uint4* w2base = reinterpret_cast<const uint4*>(W2p)
            + ((size_t)(e * 32 + w * 4) * 32 + c * 16) * 64 + lane;
        #pragma unroll
        for (int kb = 0; kb < 16; kb++) {
            bf16x8 aw[4];
            #pragma unroll
            for (int j = 0; j < 4; j++)
                aw[j] = __builtin_bit_cast(bf16x8, w2base[(size_t)(j * 32 + kb) * 64]);
            #pragma unroll
            for (int tt = 0; tt < 4; tt++) {
                int row = tt * 16 + lm;
                int bo = row * 1024 + ((kb * 64 + lg_ * 16) ^ ((row & 7) << 4));
                bf16x8 bh = __builtin_bit_cast(bf16x8,
                    *reinterpret_cast<const uint4*>(hsb + bo));
                #pragma unroll
                for (int j = 0; j < 4; j++)
                    acc2[j][tt] = __builtin_amdgcn_mfma_f32_16x16x32_bf16(aw[j], bh, acc2[j][tt], 0, 0, 0);
            }
        }
    }

    // epilogue: gate * (oT + b2) -> opair[entry][d], float4 stores
    int   ent[4];
    float gt[4];
    #pragma unroll
    for (int tt = 0; tt < 4; tt++) {
        int trow = tt * 16 + lm;
        ent[tt] = tls[trow];
        gt[tt]  = gls[trow];
    }
    #pragma unroll
    for (int j = 0; j < 4; j++) {
        int dbase = w * 64 + j * 16 + lg_ * 4;
        f32x4 b2v = *reinterpret_cast<const f32x4*>(b2 + (size_t)e * DIM + dbase);
        #pragma unroll
        for (int tt = 0; tt < 4; tt++) {
            int trow = tt * 16 + lm;
            if (trow < nvalid) {
                f32x4 o;
                #pragma unroll
                for (int r = 0; r < 4; r++) o[r] = gt[tt] * (acc2[j][tt][r] + b2v[r]);
                *reinterpret_cast<f32x4*>(opair + (size_t)ent[tt] * DIM + dbase) = o;
            }
        }
    }
}

// ---------------- combine: y[t] = opair[t][0] + opair[t][1] ----------------
__global__ __launch_bounds__(256) void combine_kernel(
    const float* __restrict__ opair, float* __restrict__ y)
{
    int n = blockIdx.x * 256 + threadIdx.x;   // over N*D/4
    int t = n >> 7, d4 = n & 127;
    const float4* o4 = (const float4*)opair;
    float4 a = o4[(size_t)(t * 2) * 128 + d4];
    float4 b = o4[(size_t)(t * 2 + 1) * 128 + d4];
    float4 r; r.x = a.x + b.x; r.y = a.y + b.y; r.z = a.z + b.z; r.w = a.w + b.w;
    reinterpret_cast<float4*>(y)[n] = r;
}

extern "C" void kernel_launch(void* const* d_in, const int* in_sizes, int n_in,
                              void* d_out, int out_size, void* d_ws, size_t ws_size,
                              hipStream_t stream)
{
    const float* x  = (const float*)d_in[0];
    const float* Wr = (const float*)d_in[1];
    const float* br = (const float*)d_in[2];
    const float* W1 = (const float*)d_in[3];
    const float* b1 = (const float*)d_in[4];
    const float* W2 = (const float*)d_in[5];
    const float* b2 = (const float*)d_in[6];
    float* y = (float*)d_out;

    char* ws = (char*)d_ws;
    int*   counts = (int*)ws;                                   // 32 B (padded 256)
    int*   tlist  = (int*)(ws + 256);                           // 256 KB
    float* glist  = (float*)(ws + 256 + 262144);                // 256 KB
    unsigned short* xb  = (unsigned short*)(ws + 256 + 524288); // 8 MB
    unsigned short* W1p = xb  + (size_t)N_TOK * DIM;            // 8 MB
    unsigned short* W2p = W1p + (size_t)NEXP * DIM * HID;       // 8 MB
    float* opair = (float*)(W2p + (size_t)NEXP * HID * DIM);    // 32 MB

    prep_kernel<<<4096, 256, 0, stream>>>(x, W1, W2, xb, W1p, W2p, counts);
    router_kernel<<<256, 256, 0, stream>>>(x, Wr, br, counts, tlist, glist);
    ffn_kernel<<<dim3(128, 8), 512, 0, stream>>>(xb, W1p, W2p, b1, b2,
                                                 counts, tlist, glist, opair);
    combine_kernel<<<4096, 256, 0, stream>>>(opair, y);
}